// Round 4
// baseline (421.279 us; speedup 1.0000x reference)
//
#include <hip/hip_runtime.h>

#define NPTS   20000
#define NCHUNK 313   // ceil(NPTS/64)

typedef __bf16 bf16x8 __attribute__((ext_vector_type(8)));
typedef float  f32x4  __attribute__((ext_vector_type(4)));

__device__ __forceinline__ unsigned short f2b(float f) {
    union { float f; unsigned int i; } v; v.f = f;
    unsigned int u = v.i;
    return (unsigned short)((u + 0x7FFFu + ((u >> 16) & 1u)) >> 16);  // RNE
}

__device__ __forceinline__ bf16x8 pack8(const float* __restrict__ f) {
    union { unsigned short s[8]; bf16x8 v; } u;
    #pragma unroll
    for (int i = 0; i < 8; ++i) u.s[i] = f2b(f[i]);
    return u.v;
}

// ============================= kernel 1: scan =============================
// Stages A (cylinder mask -> bitmaps), B (ordered first-64 extraction),
// gather (recompute rel_rot of selected points) -> ws[bs][d][64][3] fp32.
__global__ __launch_bounds__(256, 6)
void scan_kernel(const float* __restrict__ seed_xyz,
                 const float* __restrict__ pointcloud,
                 const float* __restrict__ vp_rot,
                 float* __restrict__ Xws)
{
    __shared__ unsigned long long bitmap[4][320];
    __shared__ int idxs[4][64];

    const int tid = threadIdx.x;
    const int wv  = tid >> 6;
    const int ln  = tid & 63;
    const int bs  = blockIdx.x;
    const int b   = bs >> 10;

    const float sx = seed_xyz[bs*3+0];
    const float sy = seed_xyz[bs*3+1];
    const float sz = seed_xyz[bs*3+2];
    const float R00 = vp_rot[bs*9+0], R01 = vp_rot[bs*9+1], R02 = vp_rot[bs*9+2];
    const float R10 = vp_rot[bs*9+3], R11 = vp_rot[bs*9+4], R12 = vp_rot[bs*9+5];
    const float R20 = vp_rot[bs*9+6], R21 = vp_rot[bs*9+7], R22 = vp_rot[bs*9+8];

    // ---- stage A: unroll x2 (two chunks in flight) ----
    {
        #pragma clang fp contract(off)
        for (int c0 = wv; c0 < NCHUNK; c0 += 8) {
            const int c1 = c0 + 4;
            const bool has1 = (c1 < NCHUNK);     // wave-uniform

            int n0 = c0*64 + ln;
            bool v0 = (n0 < NPTS);
            int nc0 = v0 ? n0 : (NPTS - 1);
            const float* p0 = pointcloud + (b*NPTS + nc0)*3;
            float a0 = p0[0], a1 = p0[1], a2 = p0[2];

            int n1 = c1*64 + ln;
            bool v1 = (n1 < NPTS);
            int nc1 = (has1 && v1) ? n1 : (NPTS - 1);
            const float* p1 = pointcloud + (b*NPTS + nc1)*3;
            float e0 = p1[0], e1 = p1[1], e2 = p1[2];

            {
                float rx = a0 - sx, ry = a1 - sy, rz = a2 - sz;
                float x = (rx*R00 + ry*R10) + rz*R20;
                float y = (rx*R01 + ry*R11) + rz*R21;
                float z = (rx*R02 + ry*R12) + rz*R22;
                bool mb = ((y*y + z*z) < 0.0025f) && (x > -0.02f) && v0;
                unsigned long long m0 = __ballot(mb && (x < 0.01f));
                unsigned long long m1 = __ballot(mb && (x < 0.02f));
                unsigned long long m2 = __ballot(mb && (x < 0.03f));
                unsigned long long m3 = __ballot(mb && (x < 0.04f));
                if (ln == 0) {
                    bitmap[0][c0] = m0; bitmap[1][c0] = m1;
                    bitmap[2][c0] = m2; bitmap[3][c0] = m3;
                }
            }
            if (has1) {
                float rx = e0 - sx, ry = e1 - sy, rz = e2 - sz;
                float x = (rx*R00 + ry*R10) + rz*R20;
                float y = (rx*R01 + ry*R11) + rz*R21;
                float z = (rx*R02 + ry*R12) + rz*R22;
                bool mb = ((y*y + z*z) < 0.0025f) && (x > -0.02f) && v1;
                unsigned long long m0 = __ballot(mb && (x < 0.01f));
                unsigned long long m1 = __ballot(mb && (x < 0.02f));
                unsigned long long m2 = __ballot(mb && (x < 0.03f));
                unsigned long long m3 = __ballot(mb && (x < 0.04f));
                if (ln == 0) {
                    bitmap[0][c1] = m0; bitmap[1][c1] = m1;
                    bitmap[2][c1] = m2; bitmap[3][c1] = m3;
                }
            }
        }
    }
    __syncthreads();

    // ---- stage B: ordered first-64 extraction (wave wv -> d=wv) ----
    {
        const int d = wv;
        int carry = 0;
        for (int r = 0; r < 5 && carry < 64; ++r) {
            int c = r*64 + ln;
            unsigned long long w = (c < NCHUNK) ? bitmap[d][c] : 0ULL;
            int wc = __popcll(w);
            int incl = wc;
            #pragma unroll
            for (int off = 1; off < 64; off <<= 1) {
                int t = __shfl_up(incl, off);
                if (ln >= off) incl += t;
            }
            int rank  = carry + incl - wc;
            int total = __shfl(incl, 63);
            while (w && rank < 64) {
                int bp = __builtin_ctzll(w);
                w &= w - 1;
                idxs[d][rank] = c*64 + bp;
                ++rank;
            }
            carry += total;
        }
        int cnt = carry < 64 ? carry : 64;
        int first = (cnt > 0) ? idxs[d][0] : 0;
        if (ln >= cnt) idxs[d][ln] = first;
    }
    __syncthreads();

    // ---- gather: recompute rel_rot for selected points, store to ws ----
    {
        #pragma clang fp contract(off)
        int n = idxs[wv][ln];
        const float* p = pointcloud + (b*NPTS + n)*3;
        float rx = p[0] - sx, ry = p[1] - sy, rz = p[2] - sz;
        float x = (rx*R00 + ry*R10) + rz*R20;
        float y = (rx*R01 + ry*R11) + rz*R21;
        float z = (rx*R02 + ry*R12) + rz*R22;
        float* o = Xws + bs*768 + (wv*64 + ln)*3;
        o[0] = x; o[1] = y; o[2] = z;
    }
}

// ============================= kernel 2: MLP ==============================
struct __align__(16) SMemB {
    unsigned short h1[64][72];     // [sample][ch] +8 pad
    unsigned short h2[64][136];    // [sample][ch] +8 pad
    float  X[4][64][3];
    float2 sb2[128];
    float2 sb3[256];
    float  w1e[64][3];             // BN1 absorbed into layer-1 weights
    float  b1e[64];
};

__global__ __launch_bounds__(256, 4)
void mlp_kernel(const float* __restrict__ Xws,
                const float* __restrict__ w1,
                const float* __restrict__ g1,  const float* __restrict__ be1,
                const float* __restrict__ mn1, const float* __restrict__ vr1,
                const float* __restrict__ w2,
                const float* __restrict__ g2,  const float* __restrict__ be2,
                const float* __restrict__ mn2, const float* __restrict__ vr2,
                const float* __restrict__ w3,
                const float* __restrict__ g3,  const float* __restrict__ be3,
                const float* __restrict__ mn3, const float* __restrict__ vr3,
                float* __restrict__ out)
{
    __shared__ SMemB sm;
    const int tid = threadIdx.x;
    const int wv  = tid >> 6;
    const int ln  = tid & 63;
    const int q   = ln >> 4;
    const int l15 = ln & 15;

    // XCD-aware swizzle: blocks writing the same output cache line (s..s+3)
    // share blk&7, i.e. land on the same XCD under round-robin dispatch.
    const int blk = blockIdx.x;
    const int i8  = blk >> 3;
    const int s   = (blk & 7) * 128 + (i8 & 127);
    const int b   = i8 >> 7;
    const int bs  = b * 1024 + s;

    // ---- BN constants / absorbed layer-1 weights ----
    {
        float inv = g3[tid] / sqrtf(vr3[tid] + 1e-5f);
        sm.sb3[tid] = make_float2(inv, be3[tid] - mn3[tid] * inv);
    }
    if (tid < 128) {
        float inv = g2[tid] / sqrtf(vr2[tid] + 1e-5f);
        sm.sb2[tid] = make_float2(inv, be2[tid] - mn2[tid] * inv);
    }
    if (tid < 64) {
        float inv = g1[tid] / sqrtf(vr1[tid] + 1e-5f);
        sm.w1e[tid][0] = inv * w1[tid*3+0];
        sm.w1e[tid][1] = inv * w1[tid*3+1];
        sm.w1e[tid][2] = inv * w1[tid*3+2];
        sm.b1e[tid]    = be1[tid] - mn1[tid] * inv;
    }

    // ---- load X (768 floats, coalesced) ----
    {
        const float* src = Xws + bs*768;
        float* dst = &sm.X[0][0][0];
        dst[tid]       = src[tid];
        dst[tid + 256] = src[tid + 256];
        dst[tid + 512] = src[tid + 512];
    }

    // ---- weight A-fragments: A[m=lane&15][k=quad*8+j] ----
    bf16x8 aw2[2][2], aw3[4][4];
    #pragma unroll
    for (int m = 0; m < 2; ++m)
        #pragma unroll
        for (int kk = 0; kk < 2; ++kk)
            aw2[m][kk] = pack8(w2 + ((wv*2+m)*16 + l15)*64 + kk*32 + q*8);
    #pragma unroll
    for (int m = 0; m < 4; ++m)
        #pragma unroll
        for (int kk = 0; kk < 4; ++kk)
            aw3[m][kk] = pack8(w3 + ((wv*4+m)*16 + l15)*128 + kk*32 + q*8);

    __syncthreads();

    for (int d = 0; d < 4; ++d) {
        // layer 1 (fma-only, BN absorbed): thread -> sample ln, ch wv*16..+15
        {
            float x0 = sm.X[d][ln][0];
            float x1 = sm.X[d][ln][1];
            float x2 = sm.X[d][ln][2];
            unsigned int pk[8];
            #pragma unroll
            for (int i = 0; i < 8; ++i) {
                unsigned short hv[2];
                #pragma unroll
                for (int t = 0; t < 2; ++t) {
                    int ch = wv*16 + i*2 + t;
                    float h = fmaf(x0, sm.w1e[ch][0],
                              fmaf(x1, sm.w1e[ch][1],
                              fmaf(x2, sm.w1e[ch][2], sm.b1e[ch])));
                    hv[t] = f2b(fmaxf(h, 0.f));
                }
                pk[i] = (unsigned int)hv[0] | ((unsigned int)hv[1] << 16);
            }
            uint4 u0 = make_uint4(pk[0], pk[1], pk[2], pk[3]);
            uint4 u1 = make_uint4(pk[4], pk[5], pk[6], pk[7]);
            *(uint4*)&sm.h1[ln][wv*16 + 0] = u0;
            *(uint4*)&sm.h1[ln][wv*16 + 8] = u1;
        }
        __syncthreads();

        // layer 2: M=128 (wave owns 2 M-tiles), K=64, N=64
        #pragma unroll
        for (int nt = 0; nt < 4; ++nt) {
            int n = nt*16 + l15;
            bf16x8 b0 = *(const bf16x8*)&sm.h1[n][q*8];
            bf16x8 b1 = *(const bf16x8*)&sm.h1[n][32 + q*8];
            #pragma unroll
            for (int m = 0; m < 2; ++m) {
                f32x4 acc = {0.f, 0.f, 0.f, 0.f};
                acc = __builtin_amdgcn_mfma_f32_16x16x32_bf16(aw2[m][0], b0, acc, 0, 0, 0);
                acc = __builtin_amdgcn_mfma_f32_16x16x32_bf16(aw2[m][1], b1, acc, 0, 0, 0);
                int ch0 = (wv*2+m)*16 + q*4;
                unsigned short hh[4];
                #pragma unroll
                for (int r = 0; r < 4; ++r) {
                    float2 sb = sm.sb2[ch0 + r];
                    hh[r] = f2b(fmaxf(fmaf(acc[r], sb.x, sb.y), 0.f));
                }
                uint2 pkk;
                pkk.x = (unsigned int)hh[0] | ((unsigned int)hh[1] << 16);
                pkk.y = (unsigned int)hh[2] | ((unsigned int)hh[3] << 16);
                *(uint2*)&sm.h2[n][ch0] = pkk;
            }
        }
        __syncthreads();

        // layer 3: M=256 (wave owns 4 M-tiles), K=128, fused BN+ReLU+max
        {
            float rm[4][4];
            #pragma unroll
            for (int m = 0; m < 4; ++m)
                #pragma unroll
                for (int r = 0; r < 4; ++r) rm[m][r] = 0.f;

            #pragma unroll
            for (int nt = 0; nt < 4; ++nt) {
                int n = nt*16 + l15;
                bf16x8 bb0 = *(const bf16x8*)&sm.h2[n][ 0 + q*8];
                bf16x8 bb1 = *(const bf16x8*)&sm.h2[n][32 + q*8];
                bf16x8 bb2 = *(const bf16x8*)&sm.h2[n][64 + q*8];
                bf16x8 bb3 = *(const bf16x8*)&sm.h2[n][96 + q*8];
                #pragma unroll
                for (int m = 0; m < 4; ++m) {
                    f32x4 acc = {0.f, 0.f, 0.f, 0.f};
                    acc = __builtin_amdgcn_mfma_f32_16x16x32_bf16(aw3[m][0], bb0, acc, 0, 0, 0);
                    acc = __builtin_amdgcn_mfma_f32_16x16x32_bf16(aw3[m][1], bb1, acc, 0, 0, 0);
                    acc = __builtin_amdgcn_mfma_f32_16x16x32_bf16(aw3[m][2], bb2, acc, 0, 0, 0);
                    acc = __builtin_amdgcn_mfma_f32_16x16x32_bf16(aw3[m][3], bb3, acc, 0, 0, 0);
                    int ch0 = (wv*4+m)*16 + q*4;
                    #pragma unroll
                    for (int r = 0; r < 4; ++r) {
                        float2 sb = sm.sb3[ch0 + r];
                        float v = fmaxf(fmaf(acc[r], sb.x, sb.y), 0.f);
                        rm[m][r] = fmaxf(rm[m][r], v);
                    }
                }
            }
            #pragma unroll
            for (int m = 0; m < 4; ++m) {
                #pragma unroll
                for (int r = 0; r < 4; ++r) {
                    float v = rm[m][r];
                    v = fmaxf(v, __shfl_xor(v, 1));
                    v = fmaxf(v, __shfl_xor(v, 2));
                    v = fmaxf(v, __shfl_xor(v, 4));
                    v = fmaxf(v, __shfl_xor(v, 8));
                    if (l15 == 0) {
                        int ch = (wv*4+m)*16 + q*4 + r;
                        out[((b*256 + ch)*1024 + s)*4 + d] = v;
                    }
                }
            }
        }
        __syncthreads();
    }
}

extern "C" void kernel_launch(void* const* d_in, const int* in_sizes, int n_in,
                              void* d_out, int out_size, void* d_ws, size_t ws_size,
                              hipStream_t stream) {
    (void)in_sizes; (void)n_in; (void)out_size; (void)ws_size;
    const float* seed = (const float*)d_in[0];
    const float* pc   = (const float*)d_in[1];
    const float* rot  = (const float*)d_in[2];
    const float* w1   = (const float*)d_in[3];
    const float* g1   = (const float*)d_in[4];
    const float* be1  = (const float*)d_in[5];
    const float* mn1  = (const float*)d_in[6];
    const float* vr1  = (const float*)d_in[7];
    const float* w2   = (const float*)d_in[8];
    const float* g2   = (const float*)d_in[9];
    const float* be2  = (const float*)d_in[10];
    const float* mn2  = (const float*)d_in[11];
    const float* vr2  = (const float*)d_in[12];
    const float* w3   = (const float*)d_in[13];
    const float* g3   = (const float*)d_in[14];
    const float* be3  = (const float*)d_in[15];
    const float* mn3  = (const float*)d_in[16];
    const float* vr3  = (const float*)d_in[17];

    float* Xws = (float*)d_ws;   // 2048 * 768 floats = 6.29 MB

    scan_kernel<<<dim3(2048), dim3(256), 0, stream>>>(seed, pc, rot, Xws);
    mlp_kernel<<<dim3(2048), dim3(256), 0, stream>>>(
        Xws,
        w1, g1, be1, mn1, vr1,
        w2, g2, be2, mn2, vr2,
        w3, g3, be3, mn3, vr3,
        (float*)d_out);
}

// Round 5
// 249.757 us; speedup vs baseline: 1.6868x; 1.6868x over previous
//
#include <hip/hip_runtime.h>

#define NPTS   20000
#define NCHUNK 313   // ceil(NPTS/64)

typedef __bf16 bf16x8 __attribute__((ext_vector_type(8)));
typedef float  f32x4  __attribute__((ext_vector_type(4)));

__device__ __forceinline__ unsigned short f2b(float f) {
    union { float f; unsigned int i; } v; v.f = f;
    unsigned int u = v.i;
    return (unsigned short)((u + 0x7FFFu + ((u >> 16) & 1u)) >> 16);  // RNE
}

// load 8 consecutive floats as two float4s, convert to bf16x8
__device__ __forceinline__ bf16x8 pack8v(const float* __restrict__ f) {
    f32x4 a = *(const f32x4*)(f);
    f32x4 c = *(const f32x4*)(f + 4);
    union { unsigned short s[8]; bf16x8 v; } u;
    #pragma unroll
    for (int i = 0; i < 4; ++i) u.s[i]     = f2b(a[i]);
    #pragma unroll
    for (int i = 0; i < 4; ++i) u.s[i + 4] = f2b(c[i]);
    return u.v;
}

// ============================= kernel 1: scan =============================
__global__ __launch_bounds__(256, 6)
void scan_kernel(const float* __restrict__ seed_xyz,
                 const float* __restrict__ pointcloud,
                 const float* __restrict__ vp_rot,
                 float* __restrict__ Xws)
{
    __shared__ unsigned long long bitmap[4][320];
    __shared__ int idxs[4][64];

    const int tid = threadIdx.x;
    const int wv  = tid >> 6;
    const int ln  = tid & 63;
    const int bs  = blockIdx.x;
    const int b   = bs >> 10;

    const float sx = seed_xyz[bs*3+0];
    const float sy = seed_xyz[bs*3+1];
    const float sz = seed_xyz[bs*3+2];
    const float R00 = vp_rot[bs*9+0], R01 = vp_rot[bs*9+1], R02 = vp_rot[bs*9+2];
    const float R10 = vp_rot[bs*9+3], R11 = vp_rot[bs*9+4], R12 = vp_rot[bs*9+5];
    const float R20 = vp_rot[bs*9+6], R21 = vp_rot[bs*9+7], R22 = vp_rot[bs*9+8];

    // ---- stage A: unroll x2 (two chunks in flight) ----
    {
        #pragma clang fp contract(off)
        for (int c0 = wv; c0 < NCHUNK; c0 += 8) {
            const int c1 = c0 + 4;
            const bool has1 = (c1 < NCHUNK);     // wave-uniform

            int n0 = c0*64 + ln;
            bool v0 = (n0 < NPTS);
            int nc0 = v0 ? n0 : (NPTS - 1);
            const float* p0 = pointcloud + (b*NPTS + nc0)*3;
            float a0 = p0[0], a1 = p0[1], a2 = p0[2];

            int n1 = c1*64 + ln;
            bool v1 = (n1 < NPTS);
            int nc1 = (has1 && v1) ? n1 : (NPTS - 1);
            const float* p1 = pointcloud + (b*NPTS + nc1)*3;
            float e0 = p1[0], e1 = p1[1], e2 = p1[2];

            {
                float rx = a0 - sx, ry = a1 - sy, rz = a2 - sz;
                float x = (rx*R00 + ry*R10) + rz*R20;
                float y = (rx*R01 + ry*R11) + rz*R21;
                float z = (rx*R02 + ry*R12) + rz*R22;
                bool mb = ((y*y + z*z) < 0.0025f) && (x > -0.02f) && v0;
                unsigned long long m0 = __ballot(mb && (x < 0.01f));
                unsigned long long m1 = __ballot(mb && (x < 0.02f));
                unsigned long long m2 = __ballot(mb && (x < 0.03f));
                unsigned long long m3 = __ballot(mb && (x < 0.04f));
                if (ln == 0) {
                    bitmap[0][c0] = m0; bitmap[1][c0] = m1;
                    bitmap[2][c0] = m2; bitmap[3][c0] = m3;
                }
            }
            if (has1) {
                float rx = e0 - sx, ry = e1 - sy, rz = e2 - sz;
                float x = (rx*R00 + ry*R10) + rz*R20;
                float y = (rx*R01 + ry*R11) + rz*R21;
                float z = (rx*R02 + ry*R12) + rz*R22;
                bool mb = ((y*y + z*z) < 0.0025f) && (x > -0.02f) && v1;
                unsigned long long m0 = __ballot(mb && (x < 0.01f));
                unsigned long long m1 = __ballot(mb && (x < 0.02f));
                unsigned long long m2 = __ballot(mb && (x < 0.03f));
                unsigned long long m3 = __ballot(mb && (x < 0.04f));
                if (ln == 0) {
                    bitmap[0][c1] = m0; bitmap[1][c1] = m1;
                    bitmap[2][c1] = m2; bitmap[3][c1] = m3;
                }
            }
        }
    }
    __syncthreads();

    // ---- stage B: ordered first-64 extraction (wave wv -> d=wv) ----
    {
        const int d = wv;
        int carry = 0;
        for (int r = 0; r < 5 && carry < 64; ++r) {
            int c = r*64 + ln;
            unsigned long long w = (c < NCHUNK) ? bitmap[d][c] : 0ULL;
            int wc = __popcll(w);
            int incl = wc;
            #pragma unroll
            for (int off = 1; off < 64; off <<= 1) {
                int t = __shfl_up(incl, off);
                if (ln >= off) incl += t;
            }
            int rank  = carry + incl - wc;
            int total = __shfl(incl, 63);
            while (w && rank < 64) {
                int bp = __builtin_ctzll(w);
                w &= w - 1;
                idxs[d][rank] = c*64 + bp;
                ++rank;
            }
            carry += total;
        }
        int cnt = carry < 64 ? carry : 64;
        int first = (cnt > 0) ? idxs[d][0] : 0;
        if (ln >= cnt) idxs[d][ln] = first;
    }
    __syncthreads();

    // ---- gather: recompute rel_rot for selected points, store to ws ----
    {
        #pragma clang fp contract(off)
        int n = idxs[wv][ln];
        const float* p = pointcloud + (b*NPTS + n)*3;
        float rx = p[0] - sx, ry = p[1] - sy, rz = p[2] - sz;
        float x = (rx*R00 + ry*R10) + rz*R20;
        float y = (rx*R01 + ry*R11) + rz*R21;
        float z = (rx*R02 + ry*R12) + rz*R22;
        float* o = Xws + bs*768 + (wv*64 + ln)*3;
        o[0] = x; o[1] = y; o[2] = z;
    }
}

// ============================= kernel 2: MLP ==============================
struct __align__(16) SMemB {
    unsigned short h1[64][72];     // [sample][ch] +8 pad
    unsigned short h2[64][136];    // [sample][ch] +8 pad
    float  X[4][64][3];
    float2 sb2[128];
    float2 sb3[256];
    float  w1e[64][3];             // BN1 absorbed into layer-1 weights
    float  b1e[64];
};

// NOTE: launch_bounds min-waves MUST stay at 2. (256,4) caps VGPR at 128 ->
// the 80-reg weight fragments spill to scratch -> ~1 GB of HBM traffic
// (measured R4: FETCH 578 MB / WRITE 481 MB, 291 us). (256,2) held them
// in regs in R3 with zero spill (FETCH 10.9 MB).
__global__ __launch_bounds__(256, 2)
void mlp_kernel(const float* __restrict__ Xws,
                const float* __restrict__ w1,
                const float* __restrict__ g1,  const float* __restrict__ be1,
                const float* __restrict__ mn1, const float* __restrict__ vr1,
                const float* __restrict__ w2,
                const float* __restrict__ g2,  const float* __restrict__ be2,
                const float* __restrict__ mn2, const float* __restrict__ vr2,
                const float* __restrict__ w3,
                const float* __restrict__ g3,  const float* __restrict__ be3,
                const float* __restrict__ mn3, const float* __restrict__ vr3,
                float* __restrict__ out)
{
    __shared__ SMemB sm;
    const int tid = threadIdx.x;
    const int wv  = tid >> 6;
    const int ln  = tid & 63;
    const int q   = ln >> 4;
    const int l15 = ln & 15;

    // XCD-aware swizzle: blocks writing the same output cache line (s..s+3)
    // share blk&7, i.e. land on the same XCD under round-robin dispatch.
    const int blk = blockIdx.x;
    const int i8  = blk >> 3;
    const int s   = (blk & 7) * 128 + (i8 & 127);
    const int b   = i8 >> 7;
    const int bs  = b * 1024 + s;

    // ---- BN constants / absorbed layer-1 weights ----
    {
        float inv = g3[tid] / sqrtf(vr3[tid] + 1e-5f);
        sm.sb3[tid] = make_float2(inv, be3[tid] - mn3[tid] * inv);
    }
    if (tid < 128) {
        float inv = g2[tid] / sqrtf(vr2[tid] + 1e-5f);
        sm.sb2[tid] = make_float2(inv, be2[tid] - mn2[tid] * inv);
    }
    if (tid < 64) {
        float inv = g1[tid] / sqrtf(vr1[tid] + 1e-5f);
        sm.w1e[tid][0] = inv * w1[tid*3+0];
        sm.w1e[tid][1] = inv * w1[tid*3+1];
        sm.w1e[tid][2] = inv * w1[tid*3+2];
        sm.b1e[tid]    = be1[tid] - mn1[tid] * inv;
    }

    // ---- load X (768 floats, coalesced) ----
    {
        const float* src = Xws + bs*768;
        float* dst = &sm.X[0][0][0];
        dst[tid]       = src[tid];
        dst[tid + 256] = src[tid + 256];
        dst[tid + 512] = src[tid + 512];
    }

    // ---- weight A-fragments: A[m=lane&15][k=quad*8+j] ----
    bf16x8 aw2[2][2], aw3[4][4];
    #pragma unroll
    for (int m = 0; m < 2; ++m)
        #pragma unroll
        for (int kk = 0; kk < 2; ++kk)
            aw2[m][kk] = pack8v(w2 + ((wv*2+m)*16 + l15)*64 + kk*32 + q*8);
    #pragma unroll
    for (int m = 0; m < 4; ++m)
        #pragma unroll
        for (int kk = 0; kk < 4; ++kk)
            aw3[m][kk] = pack8v(w3 + ((wv*4+m)*16 + l15)*128 + kk*32 + q*8);

    __syncthreads();

    for (int d = 0; d < 4; ++d) {
        // layer 1 (fma-only, BN absorbed): thread -> sample ln, ch wv*16..+15
        {
            float x0 = sm.X[d][ln][0];
            float x1 = sm.X[d][ln][1];
            float x2 = sm.X[d][ln][2];
            unsigned int pk[8];
            #pragma unroll
            for (int i = 0; i < 8; ++i) {
                unsigned short hv[2];
                #pragma unroll
                for (int t = 0; t < 2; ++t) {
                    int ch = wv*16 + i*2 + t;
                    float h = fmaf(x0, sm.w1e[ch][0],
                              fmaf(x1, sm.w1e[ch][1],
                              fmaf(x2, sm.w1e[ch][2], sm.b1e[ch])));
                    hv[t] = f2b(fmaxf(h, 0.f));
                }
                pk[i] = (unsigned int)hv[0] | ((unsigned int)hv[1] << 16);
            }
            uint4 u0 = make_uint4(pk[0], pk[1], pk[2], pk[3]);
            uint4 u1 = make_uint4(pk[4], pk[5], pk[6], pk[7]);
            *(uint4*)&sm.h1[ln][wv*16 + 0] = u0;
            *(uint4*)&sm.h1[ln][wv*16 + 8] = u1;
        }
        __syncthreads();

        // layer 2: M=128 (wave owns 2 M-tiles), K=64, N=64
        #pragma unroll
        for (int nt = 0; nt < 4; ++nt) {
            int n = nt*16 + l15;
            bf16x8 b0 = *(const bf16x8*)&sm.h1[n][q*8];
            bf16x8 b1 = *(const bf16x8*)&sm.h1[n][32 + q*8];
            #pragma unroll
            for (int m = 0; m < 2; ++m) {
                f32x4 acc = {0.f, 0.f, 0.f, 0.f};
                acc = __builtin_amdgcn_mfma_f32_16x16x32_bf16(aw2[m][0], b0, acc, 0, 0, 0);
                acc = __builtin_amdgcn_mfma_f32_16x16x32_bf16(aw2[m][1], b1, acc, 0, 0, 0);
                int ch0 = (wv*2+m)*16 + q*4;
                unsigned short hh[4];
                #pragma unroll
                for (int r = 0; r < 4; ++r) {
                    float2 sb = sm.sb2[ch0 + r];
                    hh[r] = f2b(fmaxf(fmaf(acc[r], sb.x, sb.y), 0.f));
                }
                uint2 pkk;
                pkk.x = (unsigned int)hh[0] | ((unsigned int)hh[1] << 16);
                pkk.y = (unsigned int)hh[2] | ((unsigned int)hh[3] << 16);
                *(uint2*)&sm.h2[n][ch0] = pkk;
            }
        }
        __syncthreads();

        // layer 3: M=256 (wave owns 4 M-tiles), K=128, fused BN+ReLU+max
        {
            float rm[4][4];
            #pragma unroll
            for (int m = 0; m < 4; ++m)
                #pragma unroll
                for (int r = 0; r < 4; ++r) rm[m][r] = 0.f;

            #pragma unroll
            for (int nt = 0; nt < 4; ++nt) {
                int n = nt*16 + l15;
                bf16x8 bb0 = *(const bf16x8*)&sm.h2[n][ 0 + q*8];
                bf16x8 bb1 = *(const bf16x8*)&sm.h2[n][32 + q*8];
                bf16x8 bb2 = *(const bf16x8*)&sm.h2[n][64 + q*8];
                bf16x8 bb3 = *(const bf16x8*)&sm.h2[n][96 + q*8];
                #pragma unroll
                for (int m = 0; m < 4; ++m) {
                    f32x4 acc = {0.f, 0.f, 0.f, 0.f};
                    acc = __builtin_amdgcn_mfma_f32_16x16x32_bf16(aw3[m][0], bb0, acc, 0, 0, 0);
                    acc = __builtin_amdgcn_mfma_f32_16x16x32_bf16(aw3[m][1], bb1, acc, 0, 0, 0);
                    acc = __builtin_amdgcn_mfma_f32_16x16x32_bf16(aw3[m][2], bb2, acc, 0, 0, 0);
                    acc = __builtin_amdgcn_mfma_f32_16x16x32_bf16(aw3[m][3], bb3, acc, 0, 0, 0);
                    int ch0 = (wv*4+m)*16 + q*4;
                    #pragma unroll
                    for (int r = 0; r < 4; ++r) {
                        float2 sb = sm.sb3[ch0 + r];
                        float v = fmaxf(fmaf(acc[r], sb.x, sb.y), 0.f);
                        rm[m][r] = fmaxf(rm[m][r], v);
                    }
                }
            }
            #pragma unroll
            for (int m = 0; m < 4; ++m) {
                #pragma unroll
                for (int r = 0; r < 4; ++r) {
                    float v = rm[m][r];
                    v = fmaxf(v, __shfl_xor(v, 1));
                    v = fmaxf(v, __shfl_xor(v, 2));
                    v = fmaxf(v, __shfl_xor(v, 4));
                    v = fmaxf(v, __shfl_xor(v, 8));
                    if (l15 == 0) {
                        int ch = (wv*4+m)*16 + q*4 + r;
                        out[((b*256 + ch)*1024 + s)*4 + d] = v;
                    }
                }
            }
        }
        __syncthreads();
    }
}

extern "C" void kernel_launch(void* const* d_in, const int* in_sizes, int n_in,
                              void* d_out, int out_size, void* d_ws, size_t ws_size,
                              hipStream_t stream) {
    (void)in_sizes; (void)n_in; (void)out_size; (void)ws_size;
    const float* seed = (const float*)d_in[0];
    const float* pc   = (const float*)d_in[1];
    const float* rot  = (const float*)d_in[2];
    const float* w1   = (const float*)d_in[3];
    const float* g1   = (const float*)d_in[4];
    const float* be1  = (const float*)d_in[5];
    const float* mn1  = (const float*)d_in[6];
    const float* vr1  = (const float*)d_in[7];
    const float* w2   = (const float*)d_in[8];
    const float* g2   = (const float*)d_in[9];
    const float* be2  = (const float*)d_in[10];
    const float* mn2  = (const float*)d_in[11];
    const float* vr2  = (const float*)d_in[12];
    const float* w3   = (const float*)d_in[13];
    const float* g3   = (const float*)d_in[14];
    const float* be3  = (const float*)d_in[15];
    const float* mn3  = (const float*)d_in[16];
    const float* vr3  = (const float*)d_in[17];

    float* Xws = (float*)d_ws;   // 2048 * 768 floats = 6.29 MB

    scan_kernel<<<dim3(2048), dim3(256), 0, stream>>>(seed, pc, rot, Xws);
    mlp_kernel<<<dim3(2048), dim3(256), 0, stream>>>(
        Xws,
        w1, g1, be1, mn1, vr1,
        w2, g2, be2, mn2, vr2,
        w3, g3, be3, mn3, vr3,
        (float*)d_out);
}